// Round 1
// baseline (1967.508 us; speedup 1.0000x reference)
//
#include <hip/hip_runtime.h>

#define N_N 100000
#define N_E 1600000
#define N_G 5000
#define HID 256
#define IND 14

// ---- workspace layout (units of 4 bytes) ----
// zeroed region first: deg, gcnt, gsum
constexpr size_t OFF_DEG   = 0;                                   // int[N]
constexpr size_t OFF_GCNT  = 100032;                              // float[G]
constexpr size_t OFF_GSUM  = 105088;                              // float[G*HID]
constexpr size_t ZERO_END  = OFF_GSUM + (size_t)N_G * HID;        // 1385088
constexpr size_t ZERO_BYTES = ZERO_END * 4;                       // ~5.54 MB
constexpr size_t OFF_ROWP  = 1385088;                             // int[N]
constexpr size_t OFF_FILL  = 1485120;                             // int[N]
constexpr size_t OFF_BSUM  = 1585152;                             // int[128]
constexpr size_t OFF_BPRE  = 1585280;                             // int[128]
constexpr size_t OFF_INCL  = 1585408;                             // int[N]
constexpr size_t OFF_CSRC  = 1685440;                             // int[E]
constexpr size_t OFF_H1    = 3285440;                             // float[N*HID]
constexpr size_t OFF_MEAN1 = 28885440;                            // float[N*HID]
// total = 54485440 floats = ~218 MB of ws

// ---- degree count (by dst) ----
__global__ __launch_bounds__(256) void k_deg(const int* __restrict__ ei, int* __restrict__ deg) {
    int e = blockIdx.x * 256 + threadIdx.x;
    if (e < N_E) atomicAdd(&deg[ei[N_E + e]], 1);
}

// ---- 3-kernel exclusive scan of deg -> rowptr ----
__global__ __launch_bounds__(1024) void k_scanA(const int* __restrict__ deg, int* __restrict__ incl,
                                                int* __restrict__ bsum) {
    __shared__ int s[1024];
    int i = blockIdx.x * 1024 + threadIdx.x;
    s[threadIdx.x] = (i < N_N) ? deg[i] : 0;
    __syncthreads();
    for (int off = 1; off < 1024; off <<= 1) {
        int t = (threadIdx.x >= (unsigned)off) ? s[threadIdx.x - off] : 0;
        __syncthreads();
        s[threadIdx.x] += t;
        __syncthreads();
    }
    if (i < N_N) incl[i] = s[threadIdx.x];
    if (threadIdx.x == 1023) bsum[blockIdx.x] = s[1023];
}

__global__ void k_scanB(const int* __restrict__ bsum, int* __restrict__ bpre, int nblk) {
    if (threadIdx.x == 0 && blockIdx.x == 0) {
        int run = 0;
        for (int b = 0; b < nblk; b++) { bpre[b] = run; run += bsum[b]; }
    }
}

__global__ __launch_bounds__(256) void k_scanC(const int* __restrict__ incl, const int* __restrict__ deg,
                                               const int* __restrict__ bpre, const int* __restrict__ batch,
                                               int* __restrict__ rowp, int* __restrict__ fillp,
                                               float* __restrict__ gcnt) {
    int i = blockIdx.x * 256 + threadIdx.x;
    if (i < N_N) {
        int ex = bpre[i >> 10] + incl[i] - deg[i];
        rowp[i] = ex;
        fillp[i] = ex;
        atomicAdd(&gcnt[batch[i]], 1.0f);
    }
}

// ---- CSR fill: csrc[] = src ids grouped by dst ----
__global__ __launch_bounds__(256) void k_fill(const int* __restrict__ ei, int* __restrict__ fillp,
                                              int* __restrict__ csrc) {
    int e = blockIdx.x * 256 + threadIdx.x;
    if (e < N_E) {
        int d = ei[N_E + e];
        int p = atomicAdd(&fillp[d], 1);
        csrc[p] = ei[e];
    }
}

// ---- layer 1: fused CSR mean-agg (14-dim) + dual small matmul + relu ----
// 16 nodes per block; 256 threads = 256 output features each covering 16 nodes.
__global__ __launch_bounds__(256) void k_layer1(const float* __restrict__ x, const float* __restrict__ pos,
                                                const int* __restrict__ rowp, const int* __restrict__ deg,
                                                const int* __restrict__ csrc,
                                                const float* __restrict__ W1l, const float* __restrict__ b1,
                                                const float* __restrict__ W1r, float* __restrict__ h1) {
    __shared__ float ms[16][16];
    __shared__ float hs[16][16];
    int tid = threadIdx.x;
    int s = tid >> 4;
    int f = tid & 15;
    int node = blockIdx.x * 16 + s;
    if (f < IND) {
        hs[s][f] = (f < 11) ? x[node * 11 + f] : pos[node * 3 + (f - 11)];
        int st = rowp[node], dg = deg[node];
        float acc = 0.f;
        for (int e = 0; e < dg; e++) {
            int nb = csrc[st + e];
            acc += (f < 11) ? x[nb * 11 + f] : pos[nb * 3 + (f - 11)];
        }
        ms[s][f] = acc / (float)max(dg, 1);
    }
    __syncthreads();
    int j = tid;
    float bj = b1[j];
    float acc[16];
#pragma unroll
    for (int ss = 0; ss < 16; ss++) acc[ss] = bj;
#pragma unroll
    for (int k = 0; k < IND; k++) {
        float wl = W1l[k * HID + j];
        float wr = W1r[k * HID + j];
#pragma unroll
        for (int ss = 0; ss < 16; ss++)
            acc[ss] = fmaf(ms[ss][k], wl, fmaf(hs[ss][k], wr, acc[ss]));
    }
    int base = blockIdx.x * 16;
#pragma unroll
    for (int ss = 0; ss < 16; ss++)
        h1[(size_t)(base + ss) * HID + j] = fmaxf(acc[ss], 0.f);
}

// ---- layer-2 neighbor mean aggregation: one wave per node, float4 per lane ----
__global__ __launch_bounds__(256) void k_agg(const float* __restrict__ h1, const int* __restrict__ rowp,
                                             const int* __restrict__ deg, const int* __restrict__ csrc,
                                             float* __restrict__ mean1) {
    int node = blockIdx.x * 4 + (threadIdx.x >> 6);
    int lane = threadIdx.x & 63;
    int st = rowp[node], dg = deg[node];
    const float4* h1v = (const float4*)h1;
    float4 acc = make_float4(0.f, 0.f, 0.f, 0.f);
    for (int e = 0; e < dg; e++) {
        int nb = csrc[st + e];
        float4 v = h1v[(size_t)nb * 64 + lane];
        acc.x += v.x; acc.y += v.y; acc.z += v.z; acc.w += v.w;
    }
    float inv = 1.f / (float)max(dg, 1);
    float4 o; o.x = acc.x * inv; o.y = acc.y * inv; o.z = acc.z * inv; o.w = acc.w * inv;
    ((float4*)mean1)[(size_t)node * 64 + lane] = o;
}

// ---- layer 2 GEMM: C = mean1@W2l + h1@W2r + b2, relu, fused mean-pool scatter ----
// BM=64, BN=64, BK=16; 256 threads, 4x4 register tile each.
__global__ __launch_bounds__(256) void k_layer2(const float* __restrict__ mean1, const float* __restrict__ h1,
                                                const float* __restrict__ W2l, const float* __restrict__ b2,
                                                const float* __restrict__ W2r, const int* __restrict__ batch,
                                                float* __restrict__ gsum) {
    __shared__ float As[16][68];
    __shared__ float Bs[16][64];
    int tid = threadIdx.x;
    int tm = tid & 15, tn = tid >> 4;
    int bm = blockIdx.x, bn = blockIdx.y;
    float c[4][4] = {};
    int lm = tid >> 2;           // A stage: row 0..63
    int lk = (tid & 3) * 4;      // A stage: k 0,4,8,12
    int lkB = tid >> 4;          // B stage: k 0..15
    int lnB = (tid & 15) * 4;    // B stage: col 0..60
    int rowA = bm * 64 + lm;
    for (int kt = 0; kt < 32; kt++) {
        int k0 = kt * 16;
        const float* Asrc = (k0 < 256) ? mean1 : h1;
        const float* Bsrc = (k0 < 256) ? W2l : W2r;
        int kk = k0 & 255;
        float4 av = make_float4(0.f, 0.f, 0.f, 0.f);
        if (rowA < N_N) av = *(const float4*)(Asrc + (size_t)rowA * HID + kk + lk);
        float4 bv = *(const float4*)(Bsrc + (size_t)(kk + lkB) * HID + bn * 64 + lnB);
        __syncthreads();
        As[lk + 0][lm] = av.x; As[lk + 1][lm] = av.y; As[lk + 2][lm] = av.z; As[lk + 3][lm] = av.w;
        *(float4*)&Bs[lkB][lnB] = bv;
        __syncthreads();
#pragma unroll
        for (int k = 0; k < 16; k++) {
            float4 a = *(const float4*)&As[k][tm * 4];
            float4 b = *(const float4*)&Bs[k][tn * 4];
            c[0][0] = fmaf(a.x, b.x, c[0][0]); c[0][1] = fmaf(a.x, b.y, c[0][1]);
            c[0][2] = fmaf(a.x, b.z, c[0][2]); c[0][3] = fmaf(a.x, b.w, c[0][3]);
            c[1][0] = fmaf(a.y, b.x, c[1][0]); c[1][1] = fmaf(a.y, b.y, c[1][1]);
            c[1][2] = fmaf(a.y, b.z, c[1][2]); c[1][3] = fmaf(a.y, b.w, c[1][3]);
            c[2][0] = fmaf(a.z, b.x, c[2][0]); c[2][1] = fmaf(a.z, b.y, c[2][1]);
            c[2][2] = fmaf(a.z, b.z, c[2][2]); c[2][3] = fmaf(a.z, b.w, c[2][3]);
            c[3][0] = fmaf(a.w, b.x, c[3][0]); c[3][1] = fmaf(a.w, b.y, c[3][1]);
            c[3][2] = fmaf(a.w, b.z, c[3][2]); c[3][3] = fmaf(a.w, b.w, c[3][3]);
        }
    }
    int col0 = bn * 64 + tn * 4;
    float bb0 = b2[col0], bb1 = b2[col0 + 1], bb2 = b2[col0 + 2], bb3 = b2[col0 + 3];
#pragma unroll
    for (int i = 0; i < 4; i++) {
        int row = bm * 64 + tm * 4 + i;
        if (row < N_N) {
            int g = batch[row];
            float* gp = gsum + (size_t)g * HID + col0;
            atomicAdd(gp + 0, fmaxf(c[i][0] + bb0, 0.f));
            atomicAdd(gp + 1, fmaxf(c[i][1] + bb1, 0.f));
            atomicAdd(gp + 2, fmaxf(c[i][2] + bb2, 0.f));
            atomicAdd(gp + 3, fmaxf(c[i][3] + bb3, 0.f));
        }
    }
}

// ---- output head: out[g] = dot(gsum[g]/max(gcnt,1), Wout) + bout ----
__global__ __launch_bounds__(256) void k_out(const float* __restrict__ gsum, const float* __restrict__ gcnt,
                                             const float* __restrict__ Wout, const float* __restrict__ bout,
                                             float* __restrict__ out) {
    int g = blockIdx.x * 4 + (threadIdx.x >> 6);
    int lane = threadIdx.x & 63;
    if (g < N_G) {
        const float* gp = gsum + (size_t)g * HID;
        float s = 0.f;
#pragma unroll
        for (int j = 0; j < 4; j++) s = fmaf(gp[lane + j * 64], Wout[lane + j * 64], s);
#pragma unroll
        for (int off = 32; off > 0; off >>= 1) s += __shfl_down(s, off);
        if (lane == 0) out[g] = s / fmaxf(gcnt[g], 1.f) + bout[0];
    }
}

extern "C" void kernel_launch(void* const* d_in, const int* in_sizes, int n_in,
                              void* d_out, int out_size, void* d_ws, size_t ws_size,
                              hipStream_t stream) {
    const float* x    = (const float*)d_in[0];
    const float* pos  = (const float*)d_in[1];
    const int*   ei   = (const int*)d_in[2];
    const int*   batch= (const int*)d_in[3];
    const float* W1l  = (const float*)d_in[4];
    const float* b1   = (const float*)d_in[5];
    const float* W1r  = (const float*)d_in[6];
    const float* W2l  = (const float*)d_in[7];
    const float* b2   = (const float*)d_in[8];
    const float* W2r  = (const float*)d_in[9];
    const float* Wout = (const float*)d_in[10];
    const float* bout = (const float*)d_in[11];
    float* out = (float*)d_out;
    float* ws  = (float*)d_ws;

    int*   deg   = (int*)(ws + OFF_DEG);
    float* gcnt  = ws + OFF_GCNT;
    float* gsum  = ws + OFF_GSUM;
    int*   rowp  = (int*)(ws + OFF_ROWP);
    int*   fillp = (int*)(ws + OFF_FILL);
    int*   bsum  = (int*)(ws + OFF_BSUM);
    int*   bpre  = (int*)(ws + OFF_BPRE);
    int*   incl  = (int*)(ws + OFF_INCL);
    int*   csrc  = (int*)(ws + OFF_CSRC);
    float* h1    = ws + OFF_H1;
    float* mean1 = ws + OFF_MEAN1;

    hipMemsetAsync(d_ws, 0, ZERO_BYTES, stream);
    k_deg  <<<(N_E + 255) / 256, 256, 0, stream>>>(ei, deg);
    k_scanA<<<(N_N + 1023) / 1024, 1024, 0, stream>>>(deg, incl, bsum);
    k_scanB<<<1, 64, 0, stream>>>(bsum, bpre, (N_N + 1023) / 1024);
    k_scanC<<<(N_N + 255) / 256, 256, 0, stream>>>(incl, deg, bpre, batch, rowp, fillp, gcnt);
    k_fill <<<(N_E + 255) / 256, 256, 0, stream>>>(ei, fillp, csrc);
    k_layer1<<<N_N / 16, 256, 0, stream>>>(x, pos, rowp, deg, csrc, W1l, b1, W1r, h1);
    k_agg  <<<N_N / 4, 256, 0, stream>>>(h1, rowp, deg, csrc, mean1);
    k_layer2<<<dim3((N_N + 63) / 64, 4), 256, 0, stream>>>(mean1, h1, W2l, b2, W2r, batch, gsum);
    k_out  <<<(N_G + 3) / 4, 256, 0, stream>>>(gsum, gcnt, Wout, bout, out);
}

// Round 2
// 975.443 us; speedup vs baseline: 2.0170x; 2.0170x over previous
//
#include <hip/hip_runtime.h>

#define N_N 100000
#define N_E 1600000
#define N_G 5000
#define HID 256
#define IND 14

// ---- workspace layout (units of 4 bytes) ----
// zeroed region first: deg, gcnt, outsum
constexpr size_t OFF_DEG   = 0;                                   // int[N]
constexpr size_t OFF_GCNT  = 100032;                              // float[G]
constexpr size_t OFF_OUTS  = 105088;                              // float[G]
constexpr size_t ZERO_END  = OFF_OUTS + N_G;                      // 110088
constexpr size_t ZERO_BYTES = ZERO_END * 4;                       // ~0.44 MB
constexpr size_t OFF_ROWP  = 1385088;                             // int[N]
constexpr size_t OFF_FILL  = 1485120;                             // int[N]
constexpr size_t OFF_BSUM  = 1585152;                             // int[128]
constexpr size_t OFF_BPRE  = 1585280;                             // int[128]
constexpr size_t OFF_INCL  = 1585408;                             // int[N]
constexpr size_t OFF_CSRC  = 1685440;                             // int[E]
constexpr size_t OFF_H1    = 3285440;                             // float[N*HID]
constexpr size_t OFF_MEAN1 = 28885440;                            // float[N*HID]
// total = 54485440 floats = ~218 MB of ws

// ---- degree count (by dst) ----
__global__ __launch_bounds__(256) void k_deg(const int* __restrict__ ei, int* __restrict__ deg) {
    int e = blockIdx.x * 256 + threadIdx.x;
    if (e < N_E) atomicAdd(&deg[ei[N_E + e]], 1);
}

// ---- 3-kernel exclusive scan of deg -> rowptr ----
__global__ __launch_bounds__(1024) void k_scanA(const int* __restrict__ deg, int* __restrict__ incl,
                                                int* __restrict__ bsum) {
    __shared__ int s[1024];
    int i = blockIdx.x * 1024 + threadIdx.x;
    s[threadIdx.x] = (i < N_N) ? deg[i] : 0;
    __syncthreads();
    for (int off = 1; off < 1024; off <<= 1) {
        int t = (threadIdx.x >= (unsigned)off) ? s[threadIdx.x - off] : 0;
        __syncthreads();
        s[threadIdx.x] += t;
        __syncthreads();
    }
    if (i < N_N) incl[i] = s[threadIdx.x];
    if (threadIdx.x == 1023) bsum[blockIdx.x] = s[1023];
}

__global__ void k_scanB(const int* __restrict__ bsum, int* __restrict__ bpre, int nblk) {
    if (threadIdx.x == 0 && blockIdx.x == 0) {
        int run = 0;
        for (int b = 0; b < nblk; b++) { bpre[b] = run; run += bsum[b]; }
    }
}

__global__ __launch_bounds__(256) void k_scanC(const int* __restrict__ incl, const int* __restrict__ deg,
                                               const int* __restrict__ bpre, const int* __restrict__ batch,
                                               int* __restrict__ rowp, int* __restrict__ fillp,
                                               float* __restrict__ gcnt) {
    int i = blockIdx.x * 256 + threadIdx.x;
    if (i < N_N) {
        int ex = bpre[i >> 10] + incl[i] - deg[i];
        rowp[i] = ex;
        fillp[i] = ex;
        atomicAdd(&gcnt[batch[i]], 1.0f);
    }
}

// ---- CSR fill: csrc[] = src ids grouped by dst ----
__global__ __launch_bounds__(256) void k_fill(const int* __restrict__ ei, int* __restrict__ fillp,
                                              int* __restrict__ csrc) {
    int e = blockIdx.x * 256 + threadIdx.x;
    if (e < N_E) {
        int d = ei[N_E + e];
        int p = atomicAdd(&fillp[d], 1);
        csrc[p] = ei[e];
    }
}

// ---- layer 1: fused CSR mean-agg (14-dim) + dual small matmul + relu ----
__global__ __launch_bounds__(256) void k_layer1(const float* __restrict__ x, const float* __restrict__ pos,
                                                const int* __restrict__ rowp, const int* __restrict__ deg,
                                                const int* __restrict__ csrc,
                                                const float* __restrict__ W1l, const float* __restrict__ b1,
                                                const float* __restrict__ W1r, float* __restrict__ h1) {
    __shared__ float ms[16][16];
    __shared__ float hs[16][16];
    int tid = threadIdx.x;
    int s = tid >> 4;
    int f = tid & 15;
    int node = blockIdx.x * 16 + s;
    if (f < IND) {
        hs[s][f] = (f < 11) ? x[node * 11 + f] : pos[node * 3 + (f - 11)];
        int st = rowp[node], dg = deg[node];
        float acc = 0.f;
        for (int e = 0; e < dg; e++) {
            int nb = csrc[st + e];
            acc += (f < 11) ? x[nb * 11 + f] : pos[nb * 3 + (f - 11)];
        }
        ms[s][f] = acc / (float)max(dg, 1);
    }
    __syncthreads();
    int j = tid;
    float bj = b1[j];
    float acc[16];
#pragma unroll
    for (int ss = 0; ss < 16; ss++) acc[ss] = bj;
#pragma unroll
    for (int k = 0; k < IND; k++) {
        float wl = W1l[k * HID + j];
        float wr = W1r[k * HID + j];
#pragma unroll
        for (int ss = 0; ss < 16; ss++)
            acc[ss] = fmaf(ms[ss][k], wl, fmaf(hs[ss][k], wr, acc[ss]));
    }
    int base = blockIdx.x * 16;
#pragma unroll
    for (int ss = 0; ss < 16; ss++)
        h1[(size_t)(base + ss) * HID + j] = fmaxf(acc[ss], 0.f);
}

// ---- layer-2 neighbor mean aggregation: one wave per node, float4 per lane ----
__global__ __launch_bounds__(256) void k_agg(const float* __restrict__ h1, const int* __restrict__ rowp,
                                             const int* __restrict__ deg, const int* __restrict__ csrc,
                                             float* __restrict__ mean1) {
    int node = blockIdx.x * 4 + (threadIdx.x >> 6);
    int lane = threadIdx.x & 63;
    int st = rowp[node], dg = deg[node];
    const float4* h1v = (const float4*)h1;
    float4 acc = make_float4(0.f, 0.f, 0.f, 0.f);
    for (int e = 0; e < dg; e++) {
        int nb = csrc[st + e];
        float4 v = h1v[(size_t)nb * 64 + lane];
        acc.x += v.x; acc.y += v.y; acc.z += v.z; acc.w += v.w;
    }
    float inv = 1.f / (float)max(dg, 1);
    float4 o; o.x = acc.x * inv; o.y = acc.y * inv; o.z = acc.z * inv; o.w = acc.w * inv;
    ((float4*)mean1)[(size_t)node * 64 + lane] = o;
}

// ---- layer 2 GEMM + fused head ----
// C_row = relu(mean1@W2l + h1@W2r + b2); outsum[batch[row]] += dot(C_row, Wout)
// BM=64, BN=256 (full width, A read once), BK=16; 256 threads, 4x16 tile each.
// h2 is never materialized; one scalar atomic per row.
__global__ __launch_bounds__(256) void k_layer2(const float* __restrict__ mean1, const float* __restrict__ h1,
                                                const float* __restrict__ W2l, const float* __restrict__ b2,
                                                const float* __restrict__ W2r, const int* __restrict__ batch,
                                                const float* __restrict__ Wout,
                                                float* __restrict__ outsum) {
    __shared__ float As[16][68];
    __shared__ float Bs[16][256];
    __shared__ float srow[16][68];
    int tid = threadIdx.x;
    int tm = tid & 15, tn = tid >> 4;        // rows tm*4..+3, cols tn*16..+15
    int bm = blockIdx.x;
    float c[4][16] = {};
    int lm = tid >> 2;           // A stage: row 0..63
    int lk = (tid & 3) * 4;      // A stage: k 0,4,8,12
    int lkB = tid >> 4;          // B stage: k 0..15
    int lnB = (tid & 15) * 16;   // B stage: col base (4 float4s)
    int rowA = bm * 64 + lm;
    for (int kt = 0; kt < 32; kt++) {
        int k0 = kt * 16;
        const float* Asrc = (k0 < 256) ? mean1 : h1;
        const float* Bsrc = (k0 < 256) ? W2l : W2r;
        int kk = k0 & 255;
        float4 av = make_float4(0.f, 0.f, 0.f, 0.f);
        if (rowA < N_N) av = *(const float4*)(Asrc + (size_t)rowA * HID + kk + lk);
        float4 bv0 = *(const float4*)(Bsrc + (size_t)(kk + lkB) * HID + lnB + 0);
        float4 bv1 = *(const float4*)(Bsrc + (size_t)(kk + lkB) * HID + lnB + 4);
        float4 bv2 = *(const float4*)(Bsrc + (size_t)(kk + lkB) * HID + lnB + 8);
        float4 bv3 = *(const float4*)(Bsrc + (size_t)(kk + lkB) * HID + lnB + 12);
        __syncthreads();
        As[lk + 0][lm] = av.x; As[lk + 1][lm] = av.y; As[lk + 2][lm] = av.z; As[lk + 3][lm] = av.w;
        *(float4*)&Bs[lkB][lnB + 0]  = bv0;
        *(float4*)&Bs[lkB][lnB + 4]  = bv1;
        *(float4*)&Bs[lkB][lnB + 8]  = bv2;
        *(float4*)&Bs[lkB][lnB + 12] = bv3;
        __syncthreads();
#pragma unroll
        for (int k = 0; k < 16; k++) {
            float4 a = *(const float4*)&As[k][tm * 4];
            float av4[4] = {a.x, a.y, a.z, a.w};
#pragma unroll
            for (int jj = 0; jj < 4; jj++) {
                float4 b = *(const float4*)&Bs[k][tn * 16 + jj * 4];
#pragma unroll
                for (int i = 0; i < 4; i++) {
                    c[i][jj * 4 + 0] = fmaf(av4[i], b.x, c[i][jj * 4 + 0]);
                    c[i][jj * 4 + 1] = fmaf(av4[i], b.y, c[i][jj * 4 + 1]);
                    c[i][jj * 4 + 2] = fmaf(av4[i], b.z, c[i][jj * 4 + 2]);
                    c[i][jj * 4 + 3] = fmaf(av4[i], b.w, c[i][jj * 4 + 3]);
                }
            }
        }
    }
    // epilogue: per-thread partial dot over its 16 cols, LDS-reduce over tn,
    // then ONE scalar atomic per row.
    float bb[16], wo[16];
#pragma unroll
    for (int j = 0; j < 16; j++) { bb[j] = b2[tn * 16 + j]; wo[j] = Wout[tn * 16 + j]; }
#pragma unroll
    for (int i = 0; i < 4; i++) {
        float p = 0.f;
#pragma unroll
        for (int j = 0; j < 16; j++)
            p = fmaf(fmaxf(c[i][j] + bb[j], 0.f), wo[j], p);
        srow[tn][tm * 4 + i] = p;
    }
    __syncthreads();
    if (tid < 64) {
        float s = 0.f;
#pragma unroll
        for (int t = 0; t < 16; t++) s += srow[t][tid];
        int row = bm * 64 + tid;
        if (row < N_N) atomicAdd(&outsum[batch[row]], s);
    }
}

// ---- output head: out[g] = outsum[g]/max(gcnt,1) + bout ----
__global__ __launch_bounds__(256) void k_out(const float* __restrict__ outsum, const float* __restrict__ gcnt,
                                             const float* __restrict__ bout, float* __restrict__ out) {
    int g = blockIdx.x * 256 + threadIdx.x;
    if (g < N_G) out[g] = outsum[g] / fmaxf(gcnt[g], 1.f) + bout[0];
}

extern "C" void kernel_launch(void* const* d_in, const int* in_sizes, int n_in,
                              void* d_out, int out_size, void* d_ws, size_t ws_size,
                              hipStream_t stream) {
    const float* x    = (const float*)d_in[0];
    const float* pos  = (const float*)d_in[1];
    const int*   ei   = (const int*)d_in[2];
    const int*   batch= (const int*)d_in[3];
    const float* W1l  = (const float*)d_in[4];
    const float* b1   = (const float*)d_in[5];
    const float* W1r  = (const float*)d_in[6];
    const float* W2l  = (const float*)d_in[7];
    const float* b2   = (const float*)d_in[8];
    const float* W2r  = (const float*)d_in[9];
    const float* Wout = (const float*)d_in[10];
    const float* bout = (const float*)d_in[11];
    float* out = (float*)d_out;
    float* ws  = (float*)d_ws;

    int*   deg   = (int*)(ws + OFF_DEG);
    float* gcnt  = ws + OFF_GCNT;
    float* outs  = ws + OFF_OUTS;
    int*   rowp  = (int*)(ws + OFF_ROWP);
    int*   fillp = (int*)(ws + OFF_FILL);
    int*   bsum  = (int*)(ws + OFF_BSUM);
    int*   bpre  = (int*)(ws + OFF_BPRE);
    int*   incl  = (int*)(ws + OFF_INCL);
    int*   csrc  = (int*)(ws + OFF_CSRC);
    float* h1    = ws + OFF_H1;
    float* mean1 = ws + OFF_MEAN1;

    hipMemsetAsync(d_ws, 0, ZERO_BYTES, stream);
    k_deg  <<<(N_E + 255) / 256, 256, 0, stream>>>(ei, deg);
    k_scanA<<<(N_N + 1023) / 1024, 1024, 0, stream>>>(deg, incl, bsum);
    k_scanB<<<1, 64, 0, stream>>>(bsum, bpre, (N_N + 1023) / 1024);
    k_scanC<<<(N_N + 255) / 256, 256, 0, stream>>>(incl, deg, bpre, batch, rowp, fillp, gcnt);
    k_fill <<<(N_E + 255) / 256, 256, 0, stream>>>(ei, fillp, csrc);
    k_layer1<<<N_N / 16, 256, 0, stream>>>(x, pos, rowp, deg, csrc, W1l, b1, W1r, h1);
    k_agg  <<<N_N / 4, 256, 0, stream>>>(h1, rowp, deg, csrc, mean1);
    k_layer2<<<(N_N + 63) / 64, 256, 0, stream>>>(mean1, h1, W2l, b2, W2r, batch, Wout, outs);
    k_out  <<<(N_G + 255) / 256, 256, 0, stream>>>(outs, gcnt, bout, out);
}

// Round 3
// 626.556 us; speedup vs baseline: 3.1402x; 1.5568x over previous
//
#include <hip/hip_runtime.h>

#define N_N 100000
#define N_E 1600000
#define N_G 5000
#define HID 256
#define IND 14

typedef __bf16 bf16x8 __attribute__((ext_vector_type(8)));
typedef float f32x4 __attribute__((ext_vector_type(4)));
typedef unsigned short u16;
typedef unsigned int u32;

// ---- workspace layout (units of 4 bytes) ----
constexpr size_t OFF_DEG   = 0;         // int[N]
constexpr size_t OFF_GCNT  = 100032;    // float[G]
constexpr size_t OFF_OUTS  = 105088;    // float[G]
constexpr size_t ZERO_END  = 110088;
constexpr size_t ZERO_BYTES = ZERO_END * 4;
constexpr size_t OFF_ROWP  = 110592;    // int[N]
constexpr size_t OFF_FILL  = 210624;    // int[N]
constexpr size_t OFF_BSUM  = 310656;    // int[128]
constexpr size_t OFF_BPRE  = 310784;    // int[128]
constexpr size_t OFF_INCL  = 310912;    // int[N]
constexpr size_t OFF_CSRC  = 410944;    // int[E]
constexpr size_t OFF_H1B   = 2010944;   // bf16[N*256] (12.8M floats)
constexpr size_t OFF_MEAN1B= 14810944;  // bf16[N*256]
constexpr size_t OFF_WCAT  = 27610944;  // bf16[256*512]
// end = 27676480 floats = ~111 MB

__device__ __forceinline__ u16 f2b(float f) {
    u32 u = __float_as_uint(f);
    u32 r = u + 0x7FFFu + ((u >> 16) & 1u);
    return (u16)(r >> 16);
}

// ---- degree count (by dst) ----
__global__ __launch_bounds__(256) void k_deg(const int* __restrict__ ei, int* __restrict__ deg) {
    int e = blockIdx.x * 256 + threadIdx.x;
    if (e < N_E) atomicAdd(&deg[ei[N_E + e]], 1);
}

// ---- 3-kernel exclusive scan of deg -> rowptr ----
__global__ __launch_bounds__(1024) void k_scanA(const int* __restrict__ deg, int* __restrict__ incl,
                                                int* __restrict__ bsum) {
    __shared__ int s[1024];
    int i = blockIdx.x * 1024 + threadIdx.x;
    s[threadIdx.x] = (i < N_N) ? deg[i] : 0;
    __syncthreads();
    for (int off = 1; off < 1024; off <<= 1) {
        int t = (threadIdx.x >= (unsigned)off) ? s[threadIdx.x - off] : 0;
        __syncthreads();
        s[threadIdx.x] += t;
        __syncthreads();
    }
    if (i < N_N) incl[i] = s[threadIdx.x];
    if (threadIdx.x == 1023) bsum[blockIdx.x] = s[1023];
}

__global__ void k_scanB(const int* __restrict__ bsum, int* __restrict__ bpre, int nblk) {
    if (threadIdx.x == 0 && blockIdx.x == 0) {
        int run = 0;
        for (int b = 0; b < nblk; b++) { bpre[b] = run; run += bsum[b]; }
    }
}

__global__ __launch_bounds__(256) void k_scanC(const int* __restrict__ incl, const int* __restrict__ deg,
                                               const int* __restrict__ bpre, const int* __restrict__ batch,
                                               int* __restrict__ rowp, int* __restrict__ fillp,
                                               float* __restrict__ gcnt) {
    int i = blockIdx.x * 256 + threadIdx.x;
    if (i < N_N) {
        int ex = bpre[i >> 10] + incl[i] - deg[i];
        rowp[i] = ex;
        fillp[i] = ex;
        atomicAdd(&gcnt[batch[i]], 1.0f);
    }
}

// ---- CSR fill ----
__global__ __launch_bounds__(256) void k_fill(const int* __restrict__ ei, int* __restrict__ fillp,
                                              int* __restrict__ csrc) {
    int e = blockIdx.x * 256 + threadIdx.x;
    if (e < N_E) {
        int d = ei[N_E + e];
        int p = atomicAdd(&fillp[d], 1);
        csrc[p] = ei[e];
    }
}

// ---- W2 pre-transpose+concat into bf16 Wcat[n][k], k = [W2l rows | W2r rows] ----
__global__ __launch_bounds__(256) void k_wcat(const float* __restrict__ W2l, const float* __restrict__ W2r,
                                              u16* __restrict__ wcat) {
    int idx = blockIdx.x * 256 + threadIdx.x;   // 256*512
    int n = idx >> 9, k = idx & 511;
    float v = (k < 256) ? W2l[k * HID + n] : W2r[(k - 256) * HID + n];
    wcat[(size_t)n * 512 + k] = f2b(v);
}

// ---- layer 1: fused CSR mean-agg (14-dim) + dual small matmul + relu -> bf16 h1 ----
__global__ __launch_bounds__(256) void k_layer1(const float* __restrict__ x, const float* __restrict__ pos,
                                                const int* __restrict__ rowp, const int* __restrict__ deg,
                                                const int* __restrict__ csrc,
                                                const float* __restrict__ W1l, const float* __restrict__ b1,
                                                const float* __restrict__ W1r, u16* __restrict__ h1b) {
    __shared__ float ms[16][16];
    __shared__ float hs[16][16];
    int tid = threadIdx.x;
    int s = tid >> 4;
    int f = tid & 15;
    int node = blockIdx.x * 16 + s;
    if (f < IND) {
        hs[s][f] = (f < 11) ? x[node * 11 + f] : pos[node * 3 + (f - 11)];
        int st = rowp[node], dg = deg[node];
        float acc = 0.f;
        for (int e = 0; e < dg; e++) {
            int nb = csrc[st + e];
            acc += (f < 11) ? x[nb * 11 + f] : pos[nb * 3 + (f - 11)];
        }
        ms[s][f] = acc / (float)max(dg, 1);
    }
    __syncthreads();
    int j = tid;
    float bj = b1[j];
    float acc[16];
#pragma unroll
    for (int ss = 0; ss < 16; ss++) acc[ss] = bj;
#pragma unroll
    for (int k = 0; k < IND; k++) {
        float wl = W1l[k * HID + j];
        float wr = W1r[k * HID + j];
#pragma unroll
        for (int ss = 0; ss < 16; ss++)
            acc[ss] = fmaf(ms[ss][k], wl, fmaf(hs[ss][k], wr, acc[ss]));
    }
    int base = blockIdx.x * 16;
#pragma unroll
    for (int ss = 0; ss < 16; ss++)
        h1b[(size_t)(base + ss) * HID + j] = f2b(fmaxf(acc[ss], 0.f));
}

// ---- layer-2 mean aggregation on bf16 rows: 1 wave/node, 2 edges in flight ----
__global__ __launch_bounds__(256) void k_agg(const u16* __restrict__ h1b, const int* __restrict__ rowp,
                                             const int* __restrict__ deg, const int* __restrict__ csrc,
                                             u16* __restrict__ mean1b) {
    int tid = threadIdx.x;
    int node = blockIdx.x * 4 + (tid >> 6);
    int lane = tid & 63;
    int half = lane >> 5, l32 = lane & 31;
    int st = rowp[node], dg = deg[node];
    float acc[8] = {};
    for (int e = st + half; e < st + dg; e += 2) {
        int nb = csrc[e];
        uint4 v = *(const uint4*)(h1b + (size_t)nb * HID + l32 * 8);
        acc[0] += __uint_as_float(v.x << 16);
        acc[1] += __uint_as_float(v.x & 0xFFFF0000u);
        acc[2] += __uint_as_float(v.y << 16);
        acc[3] += __uint_as_float(v.y & 0xFFFF0000u);
        acc[4] += __uint_as_float(v.z << 16);
        acc[5] += __uint_as_float(v.z & 0xFFFF0000u);
        acc[6] += __uint_as_float(v.w << 16);
        acc[7] += __uint_as_float(v.w & 0xFFFF0000u);
    }
#pragma unroll
    for (int j = 0; j < 8; j++) acc[j] += __shfl_down(acc[j], 32);
    if (lane < 32) {
        float inv = 1.f / (float)max(dg, 1);
        uint4 o;
        o.x = (u32)f2b(acc[0] * inv) | ((u32)f2b(acc[1] * inv) << 16);
        o.y = (u32)f2b(acc[2] * inv) | ((u32)f2b(acc[3] * inv) << 16);
        o.z = (u32)f2b(acc[4] * inv) | ((u32)f2b(acc[5] * inv) << 16);
        o.w = (u32)f2b(acc[6] * inv) | ((u32)f2b(acc[7] * inv) << 16);
        *(uint4*)(mean1b + (size_t)node * HID + l32 * 8) = o;
    }
}

// ---- layer 2: bf16 MFMA GEMM (M=100000, N=256, K=512) + fused relu + Wout-dot + pool atomic ----
// BM=128, BN=256, BK=32; 4 waves, wave = 2 m-tiles x 16 n-tiles of 16x16x32.
__global__ __launch_bounds__(256, 2) void k_layer2(const u16* __restrict__ mean1b, const u16* __restrict__ h1b,
                                                   const u16* __restrict__ wcat, const float* __restrict__ b2,
                                                   const int* __restrict__ batch, const float* __restrict__ Wout,
                                                   float* __restrict__ outsum) {
    __shared__ u16 As[128][40];   // pad 32->40: frag reads 2-way conflict (free)
    __shared__ u16 Bs[256][40];
    int tid = threadIdx.x;
    int wave = tid >> 6, lane = tid & 63;
    int quad = lane >> 4, m16 = lane & 15;
    int bm = blockIdx.x;
    f32x4 acc[2][16] = {};
    for (int kt = 0; kt < 16; kt++) {
        const u16* Asrc = (kt < 8) ? mean1b : h1b;
        int kk = (kt & 7) * 32;
        __syncthreads();
#pragma unroll
        for (int i = 0; i < 2; i++) {            // stage A: 512 chunks of 8 bf16
            int c = tid + 256 * i;
            int r = c >> 2, kc = c & 3;
            int grow = bm * 128 + r;
            uint4 v = make_uint4(0, 0, 0, 0);
            if (grow < N_N) v = *(const uint4*)(Asrc + (size_t)grow * HID + kk + kc * 8);
            *(uint4*)&As[r][kc * 8] = v;
        }
#pragma unroll
        for (int i = 0; i < 4; i++) {            // stage B: 1024 chunks
            int c = tid + 256 * i;
            int n = c >> 2, kc = c & 3;
            uint4 v = *(const uint4*)(wcat + (size_t)n * 512 + kt * 32 + kc * 8);
            *(uint4*)&Bs[n][kc * 8] = v;
        }
        __syncthreads();
        bf16x8 afrag[2];
#pragma unroll
        for (int t = 0; t < 2; t++)
            afrag[t] = *(const bf16x8*)&As[wave * 32 + t * 16 + m16][quad * 8];
#pragma unroll
        for (int u = 0; u < 16; u++) {
            bf16x8 bfrag = *(const bf16x8*)&Bs[u * 16 + m16][quad * 8];
            acc[0][u] = __builtin_amdgcn_mfma_f32_16x16x32_bf16(afrag[0], bfrag, acc[0][u], 0, 0, 0);
            acc[1][u] = __builtin_amdgcn_mfma_f32_16x16x32_bf16(afrag[1], bfrag, acc[1][u], 0, 0, 0);
        }
    }
    // epilogue: relu + per-row dot with Wout, reduce across the 16 lanes of a quad, 1 atomic/row
    float wo[16], bb[16];
#pragma unroll
    for (int u = 0; u < 16; u++) { int col = u * 16 + m16; wo[u] = Wout[col]; bb[u] = b2[col]; }
#pragma unroll
    for (int t = 0; t < 2; t++) {
#pragma unroll
        for (int i = 0; i < 4; i++) {
            float p = 0.f;
#pragma unroll
            for (int u = 0; u < 16; u++)
                p = fmaf(fmaxf(acc[t][u][i] + bb[u], 0.f), wo[u], p);
#pragma unroll
            for (int off = 8; off > 0; off >>= 1) p += __shfl_down(p, off, 16);
            int row = bm * 128 + wave * 32 + t * 16 + quad * 4 + i;
            if (m16 == 0 && row < N_N) atomicAdd(&outsum[batch[row]], p);
        }
    }
}

// ---- output head ----
__global__ __launch_bounds__(256) void k_out(const float* __restrict__ outsum, const float* __restrict__ gcnt,
                                             const float* __restrict__ bout, float* __restrict__ out) {
    int g = blockIdx.x * 256 + threadIdx.x;
    if (g < N_G) out[g] = outsum[g] / fmaxf(gcnt[g], 1.f) + bout[0];
}

extern "C" void kernel_launch(void* const* d_in, const int* in_sizes, int n_in,
                              void* d_out, int out_size, void* d_ws, size_t ws_size,
                              hipStream_t stream) {
    const float* x    = (const float*)d_in[0];
    const float* pos  = (const float*)d_in[1];
    const int*   ei   = (const int*)d_in[2];
    const int*   batch= (const int*)d_in[3];
    const float* W1l  = (const float*)d_in[4];
    const float* b1   = (const float*)d_in[5];
    const float* W1r  = (const float*)d_in[6];
    const float* W2l  = (const float*)d_in[7];
    const float* b2   = (const float*)d_in[8];
    const float* W2r  = (const float*)d_in[9];
    const float* Wout = (const float*)d_in[10];
    const float* bout = (const float*)d_in[11];
    float* out = (float*)d_out;
    float* ws  = (float*)d_ws;

    int*   deg   = (int*)(ws + OFF_DEG);
    float* gcnt  = ws + OFF_GCNT;
    float* outs  = ws + OFF_OUTS;
    int*   rowp  = (int*)(ws + OFF_ROWP);
    int*   fillp = (int*)(ws + OFF_FILL);
    int*   bsum  = (int*)(ws + OFF_BSUM);
    int*   bpre  = (int*)(ws + OFF_BPRE);
    int*   incl  = (int*)(ws + OFF_INCL);
    int*   csrc  = (int*)(ws + OFF_CSRC);
    u16*   h1b   = (u16*)(ws + OFF_H1B);
    u16*   mean1b= (u16*)(ws + OFF_MEAN1B);
    u16*   wcat  = (u16*)(ws + OFF_WCAT);

    hipMemsetAsync(d_ws, 0, ZERO_BYTES, stream);
    k_deg  <<<(N_E + 255) / 256, 256, 0, stream>>>(ei, deg);
    k_scanA<<<(N_N + 1023) / 1024, 1024, 0, stream>>>(deg, incl, bsum);
    k_scanB<<<1, 64, 0, stream>>>(bsum, bpre, (N_N + 1023) / 1024);
    k_scanC<<<(N_N + 255) / 256, 256, 0, stream>>>(incl, deg, bpre, batch, rowp, fillp, gcnt);
    k_fill <<<(N_E + 255) / 256, 256, 0, stream>>>(ei, fillp, csrc);
    k_wcat <<<512, 256, 0, stream>>>(W2l, W2r, wcat);
    k_layer1<<<N_N / 16, 256, 0, stream>>>(x, pos, rowp, deg, csrc, W1l, b1, W1r, h1b);
    k_agg  <<<N_N / 4, 256, 0, stream>>>(h1b, rowp, deg, csrc, mean1b);
    k_layer2<<<(N_N + 127) / 128, 256, 0, stream>>>(mean1b, h1b, wcat, b2, batch, Wout, outs);
    k_out  <<<(N_G + 255) / 256, 256, 0, stream>>>(outs, gcnt, bout, out);
}

// Round 4
// 591.256 us; speedup vs baseline: 3.3277x; 1.0597x over previous
//
#include <hip/hip_runtime.h>

#define N_N 100000
#define N_E 1600000
#define N_G 5000
#define HID 256
#define IND 14

typedef __bf16 bf16x8 __attribute__((ext_vector_type(8)));
typedef float f32x4 __attribute__((ext_vector_type(4)));
typedef unsigned short u16;
typedef unsigned int u32;

// ---- workspace layout (units of 4 bytes) ----
constexpr size_t OFF_DEG   = 0;         // int[N]
constexpr size_t OFF_GCNT  = 100032;    // float[G]
constexpr size_t OFF_OUTS  = 105088;    // float[G]
constexpr size_t ZERO_END  = 110088;
constexpr size_t ZERO_BYTES = ZERO_END * 4;
constexpr size_t OFF_ROWP  = 110592;    // int[N]
constexpr size_t OFF_FILL  = 210624;    // int[N]
constexpr size_t OFF_BSUM  = 310656;    // int[128]
constexpr size_t OFF_BPRE  = 310784;    // int[128]
constexpr size_t OFF_INCL  = 310912;    // int[N]
constexpr size_t OFF_CSRC  = 410944;    // int[E]
constexpr size_t OFF_H1B   = 2010944;   // bf16[N*256]
constexpr size_t OFF_MEAN1B= 14810944;  // bf16[N*256]
constexpr size_t OFF_WCAT  = 27610944;  // bf16[256*512]
constexpr size_t OFF_XP    = 27676480;  // float[N*16]
// end = 29276480 floats = ~117 MB

__device__ __forceinline__ u16 f2b(float f) {
    u32 u = __float_as_uint(f);
    u32 r = u + 0x7FFFu + ((u >> 16) & 1u);
    return (u16)(r >> 16);
}

// ---- degree count (by dst) ----
__global__ __launch_bounds__(256) void k_deg(const int* __restrict__ ei, int* __restrict__ deg) {
    int e = blockIdx.x * 256 + threadIdx.x;
    if (e < N_E) atomicAdd(&deg[ei[N_E + e]], 1);
}

// ---- 3-kernel exclusive scan of deg -> rowptr ----
__global__ __launch_bounds__(1024) void k_scanA(const int* __restrict__ deg, int* __restrict__ incl,
                                                int* __restrict__ bsum) {
    __shared__ int s[1024];
    int i = blockIdx.x * 1024 + threadIdx.x;
    s[threadIdx.x] = (i < N_N) ? deg[i] : 0;
    __syncthreads();
    for (int off = 1; off < 1024; off <<= 1) {
        int t = (threadIdx.x >= (unsigned)off) ? s[threadIdx.x - off] : 0;
        __syncthreads();
        s[threadIdx.x] += t;
        __syncthreads();
    }
    if (i < N_N) incl[i] = s[threadIdx.x];
    if (threadIdx.x == 1023) bsum[blockIdx.x] = s[1023];
}

__global__ void k_scanB(const int* __restrict__ bsum, int* __restrict__ bpre, int nblk) {
    if (threadIdx.x == 0 && blockIdx.x == 0) {
        int run = 0;
        for (int b = 0; b < nblk; b++) { bpre[b] = run; run += bsum[b]; }
    }
}

__global__ __launch_bounds__(256) void k_scanC(const int* __restrict__ incl, const int* __restrict__ deg,
                                               const int* __restrict__ bpre, const int* __restrict__ batch,
                                               int* __restrict__ rowp, int* __restrict__ fillp,
                                               float* __restrict__ gcnt) {
    int i = blockIdx.x * 256 + threadIdx.x;
    if (i < N_N) {
        int ex = bpre[i >> 10] + incl[i] - deg[i];
        rowp[i] = ex;
        fillp[i] = ex;
        atomicAdd(&gcnt[batch[i]], 1.0f);
    }
}

// ---- CSR fill ----
__global__ __launch_bounds__(256) void k_fill(const int* __restrict__ ei, int* __restrict__ fillp,
                                              int* __restrict__ csrc) {
    int e = blockIdx.x * 256 + threadIdx.x;
    if (e < N_E) {
        int d = ei[N_E + e];
        int p = atomicAdd(&fillp[d], 1);
        csrc[p] = ei[e];
    }
}

// ---- pack x||pos into xp[N][16] fp32 (f=14,15 zero) ----
__global__ __launch_bounds__(256) void k_pack(const float* __restrict__ x, const float* __restrict__ pos,
                                              float* __restrict__ xp) {
    int idx = blockIdx.x * 256 + threadIdx.x;   // N*16
    int n = idx >> 4, f = idx & 15;
    float v = 0.f;
    if (f < 11) v = x[n * 11 + f];
    else if (f < 14) v = pos[n * 3 + (f - 11)];
    xp[idx] = v;
}

// ---- W2 pre-transpose+concat into bf16 Wcat[n][k] ----
__global__ __launch_bounds__(256) void k_wcat(const float* __restrict__ W2l, const float* __restrict__ W2r,
                                              u16* __restrict__ wcat) {
    int idx = blockIdx.x * 256 + threadIdx.x;   // 256*512
    int n = idx >> 9, k = idx & 511;
    float v = (k < 256) ? W2l[k * HID + n] : W2r[(k - 256) * HID + n];
    wcat[(size_t)n * 512 + k] = f2b(v);
}

// ---- layer 1: wave-parallel CSR mean-agg (16 edges in flight) + dual matmul + relu -> bf16 ----
__global__ __launch_bounds__(256) void k_layer1(const float* __restrict__ xp,
                                                const int* __restrict__ rowp, const int* __restrict__ deg,
                                                const int* __restrict__ csrc,
                                                const float* __restrict__ W1l, const float* __restrict__ b1,
                                                const float* __restrict__ W1r, u16* __restrict__ h1b) {
    __shared__ float ms[16][16];
    __shared__ float hs[16][16];
    int tid = threadIdx.x;
    int wave = tid >> 6, lane = tid & 63;
    int eg = lane >> 2, c = lane & 3;
    const float4* xp4 = (const float4*)xp;
#pragma unroll
    for (int nn = 0; nn < 4; nn++) {
        int s = wave * 4 + nn;
        int node = blockIdx.x * 16 + s;      // N_N % 16 == 0: always valid
        int st = rowp[node], dg = deg[node];
        float4 a = make_float4(0.f, 0.f, 0.f, 0.f);
        for (int e = st + eg; e < st + dg; e += 16) {
            int nb = csrc[e];
            float4 v = xp4[(size_t)nb * 4 + c];
            a.x += v.x; a.y += v.y; a.z += v.z; a.w += v.w;
        }
#pragma unroll
        for (int off = 32; off >= 4; off >>= 1) {
            a.x += __shfl_down(a.x, off);
            a.y += __shfl_down(a.y, off);
            a.z += __shfl_down(a.z, off);
            a.w += __shfl_down(a.w, off);
        }
        if (lane < 4) {
            float inv = 1.f / (float)max(dg, 1);
            ms[s][c * 4 + 0] = a.x * inv;
            ms[s][c * 4 + 1] = a.y * inv;
            ms[s][c * 4 + 2] = a.z * inv;
            ms[s][c * 4 + 3] = a.w * inv;
        } else if (lane < 8) {
            int cc = lane - 4;
            float4 v = xp4[(size_t)node * 4 + cc];
            hs[s][cc * 4 + 0] = v.x;
            hs[s][cc * 4 + 1] = v.y;
            hs[s][cc * 4 + 2] = v.z;
            hs[s][cc * 4 + 3] = v.w;
        }
    }
    __syncthreads();
    int j = tid;
    float bj = b1[j];
    float acc[16];
#pragma unroll
    for (int ss = 0; ss < 16; ss++) acc[ss] = bj;
#pragma unroll
    for (int k = 0; k < IND; k++) {
        float wl = W1l[k * HID + j];
        float wr = W1r[k * HID + j];
#pragma unroll
        for (int ss = 0; ss < 16; ss++)
            acc[ss] = fmaf(ms[ss][k], wl, fmaf(hs[ss][k], wr, acc[ss]));
    }
    int base = blockIdx.x * 16;
#pragma unroll
    for (int ss = 0; ss < 16; ss++)
        h1b[(size_t)(base + ss) * HID + j] = f2b(fmaxf(acc[ss], 0.f));
}

// ---- layer-2 mean aggregation on bf16 rows: 1 wave/node, 4 rows in flight ----
__global__ __launch_bounds__(256) void k_agg(const u16* __restrict__ h1b, const int* __restrict__ rowp,
                                             const int* __restrict__ deg, const int* __restrict__ csrc,
                                             u16* __restrict__ mean1b) {
    int tid = threadIdx.x;
    int node = blockIdx.x * 4 + (tid >> 6);
    int lane = tid & 63;
    int half = lane >> 5, l32 = lane & 31;
    int st = rowp[node], dg = deg[node];
    int end = st + dg;
    float acc[8] = {};
    for (int e = st + half; e < end; e += 4) {
        int nb = csrc[e];
        uint4 v = *(const uint4*)(h1b + (size_t)nb * HID + l32 * 8);
        int e2 = e + 2;
        uint4 v2 = make_uint4(0, 0, 0, 0);
        if (e2 < end) {
            int nb2 = csrc[e2];
            v2 = *(const uint4*)(h1b + (size_t)nb2 * HID + l32 * 8);
        }
        acc[0] += __uint_as_float(v.x << 16) + __uint_as_float(v2.x << 16);
        acc[1] += __uint_as_float(v.x & 0xFFFF0000u) + __uint_as_float(v2.x & 0xFFFF0000u);
        acc[2] += __uint_as_float(v.y << 16) + __uint_as_float(v2.y << 16);
        acc[3] += __uint_as_float(v.y & 0xFFFF0000u) + __uint_as_float(v2.y & 0xFFFF0000u);
        acc[4] += __uint_as_float(v.z << 16) + __uint_as_float(v2.z << 16);
        acc[5] += __uint_as_float(v.z & 0xFFFF0000u) + __uint_as_float(v2.z & 0xFFFF0000u);
        acc[6] += __uint_as_float(v.w << 16) + __uint_as_float(v2.w << 16);
        acc[7] += __uint_as_float(v.w & 0xFFFF0000u) + __uint_as_float(v2.w & 0xFFFF0000u);
    }
#pragma unroll
    for (int j = 0; j < 8; j++) acc[j] += __shfl_down(acc[j], 32);
    if (lane < 32) {
        float inv = 1.f / (float)max(dg, 1);
        uint4 o;
        o.x = (u32)f2b(acc[0] * inv) | ((u32)f2b(acc[1] * inv) << 16);
        o.y = (u32)f2b(acc[2] * inv) | ((u32)f2b(acc[3] * inv) << 16);
        o.z = (u32)f2b(acc[4] * inv) | ((u32)f2b(acc[5] * inv) << 16);
        o.w = (u32)f2b(acc[6] * inv) | ((u32)f2b(acc[7] * inv) << 16);
        *(uint4*)(mean1b + (size_t)node * HID + l32 * 8) = o;
    }
}

// ---- layer 2: bf16 MFMA GEMM + fused relu + Wout-dot + pool atomic ----
__global__ __launch_bounds__(256, 2) void k_layer2(const u16* __restrict__ mean1b, const u16* __restrict__ h1b,
                                                   const u16* __restrict__ wcat, const float* __restrict__ b2,
                                                   const int* __restrict__ batch, const float* __restrict__ Wout,
                                                   float* __restrict__ outsum) {
    __shared__ u16 As[128][40];
    __shared__ u16 Bs[256][40];
    int tid = threadIdx.x;
    int wave = tid >> 6, lane = tid & 63;
    int quad = lane >> 4, m16 = lane & 15;
    int bm = blockIdx.x;
    f32x4 acc[2][16] = {};
    for (int kt = 0; kt < 16; kt++) {
        const u16* Asrc = (kt < 8) ? mean1b : h1b;
        int kk = (kt & 7) * 32;
        __syncthreads();
#pragma unroll
        for (int i = 0; i < 2; i++) {
            int c = tid + 256 * i;
            int r = c >> 2, kc = c & 3;
            int grow = bm * 128 + r;
            uint4 v = make_uint4(0, 0, 0, 0);
            if (grow < N_N) v = *(const uint4*)(Asrc + (size_t)grow * HID + kk + kc * 8);
            *(uint4*)&As[r][kc * 8] = v;
        }
#pragma unroll
        for (int i = 0; i < 4; i++) {
            int c = tid + 256 * i;
            int n = c >> 2, kc = c & 3;
            uint4 v = *(const uint4*)(wcat + (size_t)n * 512 + kt * 32 + kc * 8);
            *(uint4*)&Bs[n][kc * 8] = v;
        }
        __syncthreads();
        bf16x8 afrag[2];
#pragma unroll
        for (int t = 0; t < 2; t++)
            afrag[t] = *(const bf16x8*)&As[wave * 32 + t * 16 + m16][quad * 8];
#pragma unroll
        for (int u = 0; u < 16; u++) {
            bf16x8 bfrag = *(const bf16x8*)&Bs[u * 16 + m16][quad * 8];
            acc[0][u] = __builtin_amdgcn_mfma_f32_16x16x32_bf16(afrag[0], bfrag, acc[0][u], 0, 0, 0);
            acc[1][u] = __builtin_amdgcn_mfma_f32_16x16x32_bf16(afrag[1], bfrag, acc[1][u], 0, 0, 0);
        }
    }
    float wo[16], bb[16];
#pragma unroll
    for (int u = 0; u < 16; u++) { int col = u * 16 + m16; wo[u] = Wout[col]; bb[u] = b2[col]; }
#pragma unroll
    for (int t = 0; t < 2; t++) {
#pragma unroll
        for (int i = 0; i < 4; i++) {
            float p = 0.f;
#pragma unroll
            for (int u = 0; u < 16; u++)
                p = fmaf(fmaxf(acc[t][u][i] + bb[u], 0.f), wo[u], p);
#pragma unroll
            for (int off = 8; off > 0; off >>= 1) p += __shfl_down(p, off, 16);
            int row = bm * 128 + wave * 32 + t * 16 + quad * 4 + i;
            if (m16 == 0 && row < N_N) atomicAdd(&outsum[batch[row]], p);
        }
    }
}

// ---- output head ----
__global__ __launch_bounds__(256) void k_out(const float* __restrict__ outsum, const float* __restrict__ gcnt,
                                             const float* __restrict__ bout, float* __restrict__ out) {
    int g = blockIdx.x * 256 + threadIdx.x;
    if (g < N_G) out[g] = outsum[g] / fmaxf(gcnt[g], 1.f) + bout[0];
}

extern "C" void kernel_launch(void* const* d_in, const int* in_sizes, int n_in,
                              void* d_out, int out_size, void* d_ws, size_t ws_size,
                              hipStream_t stream) {
    const float* x    = (const float*)d_in[0];
    const float* pos  = (const float*)d_in[1];
    const int*   ei   = (const int*)d_in[2];
    const int*   batch= (const int*)d_in[3];
    const float* W1l  = (const float*)d_in[4];
    const float* b1   = (const float*)d_in[5];
    const float* W1r  = (const float*)d_in[6];
    const float* W2l  = (const float*)d_in[7];
    const float* b2   = (const float*)d_in[8];
    const float* W2r  = (const float*)d_in[9];
    const float* Wout = (const float*)d_in[10];
    const float* bout = (const float*)d_in[11];
    float* out = (float*)d_out;
    float* ws  = (float*)d_ws;

    int*   deg   = (int*)(ws + OFF_DEG);
    float* gcnt  = ws + OFF_GCNT;
    float* outs  = ws + OFF_OUTS;
    int*   rowp  = (int*)(ws + OFF_ROWP);
    int*   fillp = (int*)(ws + OFF_FILL);
    int*   bsum  = (int*)(ws + OFF_BSUM);
    int*   bpre  = (int*)(ws + OFF_BPRE);
    int*   incl  = (int*)(ws + OFF_INCL);
    int*   csrc  = (int*)(ws + OFF_CSRC);
    u16*   h1b   = (u16*)(ws + OFF_H1B);
    u16*   mean1b= (u16*)(ws + OFF_MEAN1B);
    u16*   wcat  = (u16*)(ws + OFF_WCAT);
    float* xp    = ws + OFF_XP;

    hipMemsetAsync(d_ws, 0, ZERO_BYTES, stream);
    k_deg  <<<(N_E + 255) / 256, 256, 0, stream>>>(ei, deg);
    k_scanA<<<(N_N + 1023) / 1024, 1024, 0, stream>>>(deg, incl, bsum);
    k_scanB<<<1, 64, 0, stream>>>(bsum, bpre, (N_N + 1023) / 1024);
    k_scanC<<<(N_N + 255) / 256, 256, 0, stream>>>(incl, deg, bpre, batch, rowp, fillp, gcnt);
    k_fill <<<(N_E + 255) / 256, 256, 0, stream>>>(ei, fillp, csrc);
    k_pack <<<(N_N * 16) / 256, 256, 0, stream>>>(x, pos, xp);
    k_wcat <<<512, 256, 0, stream>>>(W2l, W2r, wcat);
    k_layer1<<<N_N / 16, 256, 0, stream>>>(xp, rowp, deg, csrc, W1l, b1, W1r, h1b);
    k_agg  <<<N_N / 4, 256, 0, stream>>>(h1b, rowp, deg, csrc, mean1b);
    k_layer2<<<(N_N + 127) / 128, 256, 0, stream>>>(mean1b, h1b, wcat, b2, batch, Wout, outs);
    k_out  <<<(N_G + 255) / 256, 256, 0, stream>>>(outs, gcnt, bout, out);
}

// Round 5
// 493.141 us; speedup vs baseline: 3.9897x; 1.1990x over previous
//
#include <hip/hip_runtime.h>

#define N_N 100000
#define N_E 1600000
#define N_G 5000
#define HID 256
#define IND 14

#define NB 391        // buckets: dst>>8, 256 nodes each (391*256 = 100096)
#define CH 4096       // edges per binning block
#define NBLK 391      // ceil(N_E/CH)

typedef __bf16 bf16x8 __attribute__((ext_vector_type(8)));
typedef float f32x4 __attribute__((ext_vector_type(4)));
typedef unsigned short u16;
typedef unsigned int u32;

// ---- workspace layout (units of 4 bytes) ----
constexpr size_t OFF_GCNT  = 0;          // float[5120]
constexpr size_t OFF_OUTS  = 5120;       // float[5120]
constexpr size_t ZERO_END  = 10240;
constexpr size_t ZERO_BYTES = ZERO_END * 4;
constexpr size_t OFF_ROWP  = 10240;      // int[100096]
constexpr size_t OFF_DEG   = 110592;     // int[100096]
constexpr size_t OFF_BCNT  = 210944;     // int[NBLK*NB]
constexpr size_t OFF_BBASE = 363840;     // int[NB+1]
constexpr size_t OFF_EBUF  = 364288;     // u32[N_E]
constexpr size_t OFF_CSRC  = 1964288;    // int[N_E]
constexpr size_t OFF_H1B   = 3564288;    // bf16[N*256]
constexpr size_t OFF_MEAN1B= 16364288;   // bf16[N*256]
constexpr size_t OFF_WCAT  = 29164288;   // bf16[256*512]
constexpr size_t OFF_XP    = 29229824;   // float[N*16]
// end = 30829824 floats = ~123 MB

__device__ __forceinline__ u16 f2b(float f) {
    u32 u = __float_as_uint(f);
    u32 r = u + 0x7FFFu + ((u >> 16) & 1u);
    return (u16)(r >> 16);
}

// ---- phase A: per-block bucket histograms (no global atomics) ----
__global__ __launch_bounds__(256) void k_bcnt(const int* __restrict__ ei, int* __restrict__ bcnt) {
    __shared__ int hist[NB];
    int tid = threadIdx.x;
    for (int i = tid; i < NB; i += 256) hist[i] = 0;
    __syncthreads();
    int base = blockIdx.x * CH;
#pragma unroll
    for (int i = 0; i < 16; i++) {
        int e = base + i * 256 + tid;
        if (e < N_E) atomicAdd(&hist[ei[N_E + e] >> 8], 1);
    }
    __syncthreads();
    for (int i = tid; i < NB; i += 256) bcnt[(size_t)blockIdx.x * NB + i] = hist[i];
}

// ---- phase B: absolute bases per (block,bucket) + bucket bases; single block ----
__global__ __launch_bounds__(512) void k_bscan(int* __restrict__ bcnt, int* __restrict__ bbase) {
    __shared__ int sc[512];
    __shared__ int tot[512];
    int t = threadIdx.x;
    int run = 0;
    if (t < NB) {
        for (int b = 0; b < NBLK; b++) {
            size_t idx = (size_t)b * NB + t;
            int v = bcnt[idx];
            bcnt[idx] = run;          // within-column exclusive prefix
            run += v;
        }
    }
    tot[t] = (t < NB) ? run : 0;
    sc[t] = tot[t];
    __syncthreads();
    for (int off = 1; off < 512; off <<= 1) {
        int v = (t >= off) ? sc[t - off] : 0;
        __syncthreads();
        sc[t] += v;
        __syncthreads();
    }
    int colbase = sc[t] - tot[t];     // exclusive scan of totals
    if (t < NB) {
        bbase[t] = colbase;
        if (t == NB - 1) bbase[NB] = colbase + tot[t];
        for (int b = 0; b < NBLK; b++) bcnt[(size_t)b * NB + t] += colbase;
    }
}

// ---- phase C: bin edges into ebuf (LDS cursors, coalesced-ish run writes) ----
__global__ __launch_bounds__(256) void k_bfill(const int* __restrict__ ei, const int* __restrict__ bcnt,
                                               u32* __restrict__ ebuf) {
    __shared__ int cur[NB];
    int tid = threadIdx.x;
    for (int i = tid; i < NB; i += 256) cur[i] = bcnt[(size_t)blockIdx.x * NB + i];
    __syncthreads();
    int base = blockIdx.x * CH;
#pragma unroll
    for (int i = 0; i < 16; i++) {
        int e = base + i * 256 + tid;
        if (e < N_E) {
            int d = ei[N_E + e];
            int s = ei[e];
            int p = atomicAdd(&cur[d >> 8], 1);
            ebuf[p] = (u32)s | ((u32)(d & 255) << 17);
        }
    }
}

// ---- phase D: per-bucket counting sort -> csrc, deg, rowp (LDS only) ----
__global__ __launch_bounds__(256) void k_sort(const u32* __restrict__ ebuf, const int* __restrict__ bbase,
                                              int* __restrict__ csrc, int* __restrict__ deg,
                                              int* __restrict__ rowp) {
    __shared__ int degL[256];
    __shared__ int sc[256];
    __shared__ int curL[256];
    int t = threadIdx.x;
    int b = blockIdx.x;
    int bs = bbase[b], be = bbase[b + 1];
    degL[t] = 0;
    __syncthreads();
    for (int e = bs + t; e < be; e += 256)
        atomicAdd(&degL[ebuf[e] >> 17], 1);
    __syncthreads();
    int myDeg = degL[t];
    sc[t] = myDeg;
    __syncthreads();
    for (int off = 1; off < 256; off <<= 1) {
        int v = (t >= off) ? sc[t - off] : 0;
        __syncthreads();
        sc[t] += v;
        __syncthreads();
    }
    int excl = sc[t] - myDeg;
    int node = (b << 8) + t;
    if (node < N_N) {
        deg[node] = myDeg;
        rowp[node] = bs + excl;
    }
    curL[t] = bs + excl;
    __syncthreads();
    for (int e = bs + t; e < be; e += 256) {
        u32 w = ebuf[e];
        int p = atomicAdd(&curL[w >> 17], 1);
        csrc[p] = (int)(w & 0x1FFFFu);
    }
}

// ---- pack x||pos into xp[N][16] fp32 (f=14,15 zero); fold gcnt count in ----
__global__ __launch_bounds__(256) void k_pack(const float* __restrict__ x, const float* __restrict__ pos,
                                              const int* __restrict__ batch,
                                              float* __restrict__ xp, float* __restrict__ gcnt) {
    int idx = blockIdx.x * 256 + threadIdx.x;   // N*16
    int n = idx >> 4, f = idx & 15;
    float v = 0.f;
    if (f < 11) v = x[n * 11 + f];
    else if (f < 14) v = pos[n * 3 + (f - 11)];
    xp[idx] = v;
    if (f == 0) atomicAdd(&gcnt[batch[n]], 1.0f);
}

// ---- W2 pre-transpose+concat into bf16 Wcat[n][k] ----
__global__ __launch_bounds__(256) void k_wcat(const float* __restrict__ W2l, const float* __restrict__ W2r,
                                              u16* __restrict__ wcat) {
    int idx = blockIdx.x * 256 + threadIdx.x;   // 256*512
    int n = idx >> 9, k = idx & 511;
    float v = (k < 256) ? W2l[k * HID + n] : W2r[(k - 256) * HID + n];
    wcat[(size_t)n * 512 + k] = f2b(v);
}

// ---- layer 1: wave-parallel CSR mean-agg (16 edges in flight) + dual matmul + relu -> bf16 ----
__global__ __launch_bounds__(256) void k_layer1(const float* __restrict__ xp,
                                                const int* __restrict__ rowp, const int* __restrict__ deg,
                                                const int* __restrict__ csrc,
                                                const float* __restrict__ W1l, const float* __restrict__ b1,
                                                const float* __restrict__ W1r, u16* __restrict__ h1b) {
    __shared__ float ms[16][16];
    __shared__ float hs[16][16];
    int tid = threadIdx.x;
    int wave = tid >> 6, lane = tid & 63;
    int eg = lane >> 2, c = lane & 3;
    const float4* xp4 = (const float4*)xp;
#pragma unroll
    for (int nn = 0; nn < 4; nn++) {
        int s = wave * 4 + nn;
        int node = blockIdx.x * 16 + s;
        int st = rowp[node], dg = deg[node];
        float4 a = make_float4(0.f, 0.f, 0.f, 0.f);
        for (int e = st + eg; e < st + dg; e += 16) {
            int nb = csrc[e];
            float4 v = xp4[(size_t)nb * 4 + c];
            a.x += v.x; a.y += v.y; a.z += v.z; a.w += v.w;
        }
#pragma unroll
        for (int off = 32; off >= 4; off >>= 1) {
            a.x += __shfl_down(a.x, off);
            a.y += __shfl_down(a.y, off);
            a.z += __shfl_down(a.z, off);
            a.w += __shfl_down(a.w, off);
        }
        if (lane < 4) {
            float inv = 1.f / (float)max(dg, 1);
            ms[s][c * 4 + 0] = a.x * inv;
            ms[s][c * 4 + 1] = a.y * inv;
            ms[s][c * 4 + 2] = a.z * inv;
            ms[s][c * 4 + 3] = a.w * inv;
        } else if (lane < 8) {
            int cc = lane - 4;
            float4 v = xp4[(size_t)node * 4 + cc];
            hs[s][cc * 4 + 0] = v.x;
            hs[s][cc * 4 + 1] = v.y;
            hs[s][cc * 4 + 2] = v.z;
            hs[s][cc * 4 + 3] = v.w;
        }
    }
    __syncthreads();
    int j = tid;
    float bj = b1[j];
    float acc[16];
#pragma unroll
    for (int ss = 0; ss < 16; ss++) acc[ss] = bj;
#pragma unroll
    for (int k = 0; k < IND; k++) {
        float wl = W1l[k * HID + j];
        float wr = W1r[k * HID + j];
#pragma unroll
        for (int ss = 0; ss < 16; ss++)
            acc[ss] = fmaf(ms[ss][k], wl, fmaf(hs[ss][k], wr, acc[ss]));
    }
    int base = blockIdx.x * 16;
#pragma unroll
    for (int ss = 0; ss < 16; ss++)
        h1b[(size_t)(base + ss) * HID + j] = f2b(fmaxf(acc[ss], 0.f));
}

// ---- layer-2 mean aggregation on bf16 rows: 1 wave/node, 4 rows in flight ----
__global__ __launch_bounds__(256) void k_agg(const u16* __restrict__ h1b, const int* __restrict__ rowp,
                                             const int* __restrict__ deg, const int* __restrict__ csrc,
                                             u16* __restrict__ mean1b) {
    int tid = threadIdx.x;
    int node = blockIdx.x * 4 + (tid >> 6);
    int lane = tid & 63;
    int half = lane >> 5, l32 = lane & 31;
    int st = rowp[node], dg = deg[node];
    int end = st + dg;
    float acc[8] = {};
    for (int e = st + half; e < end; e += 4) {
        int nb = csrc[e];
        uint4 v = *(const uint4*)(h1b + (size_t)nb * HID + l32 * 8);
        int e2 = e + 2;
        uint4 v2 = make_uint4(0, 0, 0, 0);
        if (e2 < end) {
            int nb2 = csrc[e2];
            v2 = *(const uint4*)(h1b + (size_t)nb2 * HID + l32 * 8);
        }
        acc[0] += __uint_as_float(v.x << 16) + __uint_as_float(v2.x << 16);
        acc[1] += __uint_as_float(v.x & 0xFFFF0000u) + __uint_as_float(v2.x & 0xFFFF0000u);
        acc[2] += __uint_as_float(v.y << 16) + __uint_as_float(v2.y << 16);
        acc[3] += __uint_as_float(v.y & 0xFFFF0000u) + __uint_as_float(v2.y & 0xFFFF0000u);
        acc[4] += __uint_as_float(v.z << 16) + __uint_as_float(v2.z << 16);
        acc[5] += __uint_as_float(v.z & 0xFFFF0000u) + __uint_as_float(v2.z & 0xFFFF0000u);
        acc[6] += __uint_as_float(v.w << 16) + __uint_as_float(v2.w << 16);
        acc[7] += __uint_as_float(v.w & 0xFFFF0000u) + __uint_as_float(v2.w & 0xFFFF0000u);
    }
#pragma unroll
    for (int j = 0; j < 8; j++) acc[j] += __shfl_down(acc[j], 32);
    if (lane < 32) {
        float inv = 1.f / (float)max(dg, 1);
        uint4 o;
        o.x = (u32)f2b(acc[0] * inv) | ((u32)f2b(acc[1] * inv) << 16);
        o.y = (u32)f2b(acc[2] * inv) | ((u32)f2b(acc[3] * inv) << 16);
        o.z = (u32)f2b(acc[4] * inv) | ((u32)f2b(acc[5] * inv) << 16);
        o.w = (u32)f2b(acc[6] * inv) | ((u32)f2b(acc[7] * inv) << 16);
        *(uint4*)(mean1b + (size_t)node * HID + l32 * 8) = o;
    }
}

// ---- layer 2: bf16 MFMA GEMM + fused relu + Wout-dot + pool atomic ----
__global__ __launch_bounds__(256, 2) void k_layer2(const u16* __restrict__ mean1b, const u16* __restrict__ h1b,
                                                   const u16* __restrict__ wcat, const float* __restrict__ b2,
                                                   const int* __restrict__ batch, const float* __restrict__ Wout,
                                                   float* __restrict__ outsum) {
    __shared__ u16 As[128][40];
    __shared__ u16 Bs[256][40];
    int tid = threadIdx.x;
    int wave = tid >> 6, lane = tid & 63;
    int quad = lane >> 4, m16 = lane & 15;
    int bm = blockIdx.x;
    f32x4 acc[2][16] = {};
    for (int kt = 0; kt < 16; kt++) {
        const u16* Asrc = (kt < 8) ? mean1b : h1b;
        int kk = (kt & 7) * 32;
        __syncthreads();
#pragma unroll
        for (int i = 0; i < 2; i++) {
            int c = tid + 256 * i;
            int r = c >> 2, kc = c & 3;
            int grow = bm * 128 + r;
            uint4 v = make_uint4(0, 0, 0, 0);
            if (grow < N_N) v = *(const uint4*)(Asrc + (size_t)grow * HID + kk + kc * 8);
            *(uint4*)&As[r][kc * 8] = v;
        }
#pragma unroll
        for (int i = 0; i < 4; i++) {
            int c = tid + 256 * i;
            int n = c >> 2, kc = c & 3;
            uint4 v = *(const uint4*)(wcat + (size_t)n * 512 + kt * 32 + kc * 8);
            *(uint4*)&Bs[n][kc * 8] = v;
        }
        __syncthreads();
        bf16x8 afrag[2];
#pragma unroll
        for (int t = 0; t < 2; t++)
            afrag[t] = *(const bf16x8*)&As[wave * 32 + t * 16 + m16][quad * 8];
#pragma unroll
        for (int u = 0; u < 16; u++) {
            bf16x8 bfrag = *(const bf16x8*)&Bs[u * 16 + m16][quad * 8];
            acc[0][u] = __builtin_amdgcn_mfma_f32_16x16x32_bf16(afrag[0], bfrag, acc[0][u], 0, 0, 0);
            acc[1][u] = __builtin_amdgcn_mfma_f32_16x16x32_bf16(afrag[1], bfrag, acc[1][u], 0, 0, 0);
        }
    }
    float wo[16], bb[16];
#pragma unroll
    for (int u = 0; u < 16; u++) { int col = u * 16 + m16; wo[u] = Wout[col]; bb[u] = b2[col]; }
#pragma unroll
    for (int t = 0; t < 2; t++) {
#pragma unroll
        for (int i = 0; i < 4; i++) {
            float p = 0.f;
#pragma unroll
            for (int u = 0; u < 16; u++)
                p = fmaf(fmaxf(acc[t][u][i] + bb[u], 0.f), wo[u], p);
#pragma unroll
            for (int off = 8; off > 0; off >>= 1) p += __shfl_down(p, off, 16);
            int row = bm * 128 + wave * 32 + t * 16 + quad * 4 + i;
            if (m16 == 0 && row < N_N) atomicAdd(&outsum[batch[row]], p);
        }
    }
}

// ---- output head ----
__global__ __launch_bounds__(256) void k_out(const float* __restrict__ outsum, const float* __restrict__ gcnt,
                                             const float* __restrict__ bout, float* __restrict__ out) {
    int g = blockIdx.x * 256 + threadIdx.x;
    if (g < N_G) out[g] = outsum[g] / fmaxf(gcnt[g], 1.f) + bout[0];
}

extern "C" void kernel_launch(void* const* d_in, const int* in_sizes, int n_in,
                              void* d_out, int out_size, void* d_ws, size_t ws_size,
                              hipStream_t stream) {
    const float* x    = (const float*)d_in[0];
    const float* pos  = (const float*)d_in[1];
    const int*   ei   = (const int*)d_in[2];
    const int*   batch= (const int*)d_in[3];
    const float* W1l  = (const float*)d_in[4];
    const float* b1   = (const float*)d_in[5];
    const float* W1r  = (const float*)d_in[6];
    const float* W2l  = (const float*)d_in[7];
    const float* b2   = (const float*)d_in[8];
    const float* W2r  = (const float*)d_in[9];
    const float* Wout = (const float*)d_in[10];
    const float* bout = (const float*)d_in[11];
    float* out = (float*)d_out;
    float* ws  = (float*)d_ws;

    float* gcnt  = ws + OFF_GCNT;
    float* outs  = ws + OFF_OUTS;
    int*   rowp  = (int*)(ws + OFF_ROWP);
    int*   deg   = (int*)(ws + OFF_DEG);
    int*   bcnt  = (int*)(ws + OFF_BCNT);
    int*   bbase = (int*)(ws + OFF_BBASE);
    u32*   ebuf  = (u32*)(ws + OFF_EBUF);
    int*   csrc  = (int*)(ws + OFF_CSRC);
    u16*   h1b   = (u16*)(ws + OFF_H1B);
    u16*   mean1b= (u16*)(ws + OFF_MEAN1B);
    u16*   wcat  = (u16*)(ws + OFF_WCAT);
    float* xp    = ws + OFF_XP;

    hipMemsetAsync(d_ws, 0, ZERO_BYTES, stream);
    k_bcnt <<<NBLK, 256, 0, stream>>>(ei, bcnt);
    k_bscan<<<1, 512, 0, stream>>>(bcnt, bbase);
    k_bfill<<<NBLK, 256, 0, stream>>>(ei, bcnt, ebuf);
    k_sort <<<NB, 256, 0, stream>>>(ebuf, bbase, csrc, deg, rowp);
    k_pack <<<(N_N * 16) / 256, 256, 0, stream>>>(x, pos, batch, xp, gcnt);
    k_wcat <<<512, 256, 0, stream>>>(W2l, W2r, wcat);
    k_layer1<<<N_N / 16, 256, 0, stream>>>(xp, rowp, deg, csrc, W1l, b1, W1r, h1b);
    k_agg  <<<N_N / 4, 256, 0, stream>>>(h1b, rowp, deg, csrc, mean1b);
    k_layer2<<<(N_N + 127) / 128, 256, 0, stream>>>(mean1b, h1b, wcat, b2, batch, Wout, outs);
    k_out  <<<(N_G + 255) / 256, 256, 0, stream>>>(outs, gcnt, bout, out);
}

// Round 6
// 436.480 us; speedup vs baseline: 4.5077x; 1.1298x over previous
//
#include <hip/hip_runtime.h>

#define N_N 100000
#define N_E 1600000
#define N_G 5000
#define HID 256
#define IND 14

#define NB 391        // buckets: dst>>8, 256 nodes each (391*256 = 100096)
#define CH 4096       // edges per binning block
#define NBLK 391      // ceil(N_E/CH)

typedef __bf16 bf16x8 __attribute__((ext_vector_type(8)));
typedef float f32x4 __attribute__((ext_vector_type(4)));
typedef unsigned short u16;
typedef unsigned int u32;

// ---- workspace layout (units of 4 bytes) ----
constexpr size_t OFF_GCNT  = 0;          // float[5120]
constexpr size_t OFF_OUTS  = 5120;       // float[5120]
constexpr size_t ZERO_END  = 10240;
constexpr size_t ZERO_BYTES = ZERO_END * 4;
constexpr size_t OFF_ROWP  = 10240;      // int[100096]
constexpr size_t OFF_DEG   = 110592;     // int[100096]
constexpr size_t OFF_BCNT  = 210944;     // int[NBLK*NB]
constexpr size_t OFF_TOT   = 363840;     // int[512]
constexpr size_t OFF_BBASE = 364352;     // int[NB+1]
constexpr size_t OFF_EBUF  = 364800;     // u32[N_E]
constexpr size_t OFF_CSRC  = 1964800;    // int[N_E]
constexpr size_t OFF_H1B   = 3564800;    // bf16[N*256]
constexpr size_t OFF_MEAN1B= 16364800;   // bf16[N*256]
constexpr size_t OFF_WCAT  = 29164800;   // bf16[256*512]
constexpr size_t OFF_XP    = 29230336;   // float[N*16]
// end = 30830336 floats = ~123 MB

__device__ __forceinline__ u16 f2b(float f) {
    u32 u = __float_as_uint(f);
    u32 r = u + 0x7FFFu + ((u >> 16) & 1u);
    return (u16)(r >> 16);
}

// ---- phase A: per-block bucket histograms (no global atomics) ----
__global__ __launch_bounds__(256) void k_bcnt(const int* __restrict__ ei, int* __restrict__ bcnt) {
    __shared__ int hist[NB];
    int tid = threadIdx.x;
    for (int i = tid; i < NB; i += 256) hist[i] = 0;
    __syncthreads();
    int base = blockIdx.x * CH;
#pragma unroll
    for (int i = 0; i < 16; i++) {
        int e = base + i * 256 + tid;
        if (e < N_E) atomicAdd(&hist[ei[N_E + e] >> 8], 1);
    }
    __syncthreads();
    for (int i = tid; i < NB; i += 256) bcnt[(size_t)blockIdx.x * NB + i] = hist[i];
}

// ---- phase B1: per-bucket column scan (391 parallel blocks) ----
// bcnt[i][b] <- exclusive prefix over blocks i of counts; tot[b] = column total
__global__ __launch_bounds__(512) void k_bscanA(int* __restrict__ bcnt, int* __restrict__ tot) {
    __shared__ int sc[512];
    int t = threadIdx.x;
    int b = blockIdx.x;
    int v = (t < NBLK) ? bcnt[(size_t)t * NB + b] : 0;
    sc[t] = v;
    __syncthreads();
    for (int off = 1; off < 512; off <<= 1) {
        int u = (t >= off) ? sc[t - off] : 0;
        __syncthreads();
        sc[t] += u;
        __syncthreads();
    }
    if (t < NBLK) bcnt[(size_t)t * NB + b] = sc[t] - v;   // exclusive within column
    if (t == 511) tot[b] = sc[511];
}

// ---- phase B2: scan bucket totals -> bbase (single tiny block) ----
__global__ __launch_bounds__(512) void k_bscanB(const int* __restrict__ tot, int* __restrict__ bbase) {
    __shared__ int sc[512];
    int t = threadIdx.x;
    int v = (t < NB) ? tot[t] : 0;
    sc[t] = v;
    __syncthreads();
    for (int off = 1; off < 512; off <<= 1) {
        int u = (t >= off) ? sc[t - off] : 0;
        __syncthreads();
        sc[t] += u;
        __syncthreads();
    }
    if (t < NB) bbase[t] = sc[t] - v;
    if (t == NB - 1) bbase[NB] = sc[t];
}

// ---- phase C: bin edges into ebuf (LDS cursors; base = column prefix + bucket base) ----
__global__ __launch_bounds__(256) void k_bfill(const int* __restrict__ ei, const int* __restrict__ bcnt,
                                               const int* __restrict__ bbase, u32* __restrict__ ebuf) {
    __shared__ int cur[NB];
    int tid = threadIdx.x;
    for (int i = tid; i < NB; i += 256)
        cur[i] = bcnt[(size_t)blockIdx.x * NB + i] + bbase[i];
    __syncthreads();
    int base = blockIdx.x * CH;
#pragma unroll
    for (int i = 0; i < 16; i++) {
        int e = base + i * 256 + tid;
        if (e < N_E) {
            int d = ei[N_E + e];
            int s = ei[e];
            int p = atomicAdd(&cur[d >> 8], 1);
            ebuf[p] = (u32)s | ((u32)(d & 255) << 17);
        }
    }
}

// ---- phase D: per-bucket counting sort -> csrc, deg, rowp (LDS only) ----
__global__ __launch_bounds__(256) void k_sort(const u32* __restrict__ ebuf, const int* __restrict__ bbase,
                                              int* __restrict__ csrc, int* __restrict__ deg,
                                              int* __restrict__ rowp) {
    __shared__ int degL[256];
    __shared__ int sc[256];
    __shared__ int curL[256];
    int t = threadIdx.x;
    int b = blockIdx.x;
    int bs = bbase[b], be = bbase[b + 1];
    degL[t] = 0;
    __syncthreads();
    for (int e = bs + t; e < be; e += 256)
        atomicAdd(&degL[ebuf[e] >> 17], 1);
    __syncthreads();
    int myDeg = degL[t];
    sc[t] = myDeg;
    __syncthreads();
    for (int off = 1; off < 256; off <<= 1) {
        int v = (t >= off) ? sc[t - off] : 0;
        __syncthreads();
        sc[t] += v;
        __syncthreads();
    }
    int excl = sc[t] - myDeg;
    int node = (b << 8) + t;
    if (node < N_N) {
        deg[node] = myDeg;
        rowp[node] = bs + excl;
    }
    curL[t] = bs + excl;
    __syncthreads();
    for (int e = bs + t; e < be; e += 256) {
        u32 w = ebuf[e];
        int p = atomicAdd(&curL[w >> 17], 1);
        csrc[p] = (int)(w & 0x1FFFFu);
    }
}

// ---- pack x||pos into xp[N][16] fp32 (f=14,15 zero); fold gcnt count in ----
__global__ __launch_bounds__(256) void k_pack(const float* __restrict__ x, const float* __restrict__ pos,
                                              const int* __restrict__ batch,
                                              float* __restrict__ xp, float* __restrict__ gcnt) {
    int idx = blockIdx.x * 256 + threadIdx.x;   // N*16
    int n = idx >> 4, f = idx & 15;
    float v = 0.f;
    if (f < 11) v = x[n * 11 + f];
    else if (f < 14) v = pos[n * 3 + (f - 11)];
    xp[idx] = v;
    if (f == 0) atomicAdd(&gcnt[batch[n]], 1.0f);
}

// ---- W2 pre-transpose+concat into bf16 Wcat[n][k] ----
__global__ __launch_bounds__(256) void k_wcat(const float* __restrict__ W2l, const float* __restrict__ W2r,
                                              u16* __restrict__ wcat) {
    int idx = blockIdx.x * 256 + threadIdx.x;   // 256*512
    int n = idx >> 9, k = idx & 511;
    float v = (k < 256) ? W2l[k * HID + n] : W2r[(k - 256) * HID + n];
    wcat[(size_t)n * 512 + k] = f2b(v);
}

// ---- layer 1: wave-parallel CSR mean-agg (16 edges in flight) + dual matmul + relu -> bf16 ----
__global__ __launch_bounds__(256) void k_layer1(const float* __restrict__ xp,
                                                const int* __restrict__ rowp, const int* __restrict__ deg,
                                                const int* __restrict__ csrc,
                                                const float* __restrict__ W1l, const float* __restrict__ b1,
                                                const float* __restrict__ W1r, u16* __restrict__ h1b) {
    __shared__ float ms[16][16];
    __shared__ float hs[16][16];
    int tid = threadIdx.x;
    int wave = tid >> 6, lane = tid & 63;
    int eg = lane >> 2, c = lane & 3;
    const float4* xp4 = (const float4*)xp;
#pragma unroll
    for (int nn = 0; nn < 4; nn++) {
        int s = wave * 4 + nn;
        int node = blockIdx.x * 16 + s;
        int st = rowp[node], dg = deg[node];
        float4 a = make_float4(0.f, 0.f, 0.f, 0.f);
        for (int e = st + eg; e < st + dg; e += 16) {
            int nb = csrc[e];
            float4 v = xp4[(size_t)nb * 4 + c];
            a.x += v.x; a.y += v.y; a.z += v.z; a.w += v.w;
        }
#pragma unroll
        for (int off = 32; off >= 4; off >>= 1) {
            a.x += __shfl_down(a.x, off);
            a.y += __shfl_down(a.y, off);
            a.z += __shfl_down(a.z, off);
            a.w += __shfl_down(a.w, off);
        }
        if (lane < 4) {
            float inv = 1.f / (float)max(dg, 1);
            ms[s][c * 4 + 0] = a.x * inv;
            ms[s][c * 4 + 1] = a.y * inv;
            ms[s][c * 4 + 2] = a.z * inv;
            ms[s][c * 4 + 3] = a.w * inv;
        } else if (lane < 8) {
            int cc = lane - 4;
            float4 v = xp4[(size_t)node * 4 + cc];
            hs[s][cc * 4 + 0] = v.x;
            hs[s][cc * 4 + 1] = v.y;
            hs[s][cc * 4 + 2] = v.z;
            hs[s][cc * 4 + 3] = v.w;
        }
    }
    __syncthreads();
    int j = tid;
    float bj = b1[j];
    float acc[16];
#pragma unroll
    for (int ss = 0; ss < 16; ss++) acc[ss] = bj;
#pragma unroll
    for (int k = 0; k < IND; k++) {
        float wl = W1l[k * HID + j];
        float wr = W1r[k * HID + j];
#pragma unroll
        for (int ss = 0; ss < 16; ss++)
            acc[ss] = fmaf(ms[ss][k], wl, fmaf(hs[ss][k], wr, acc[ss]));
    }
    int base = blockIdx.x * 16;
#pragma unroll
    for (int ss = 0; ss < 16; ss++)
        h1b[(size_t)(base + ss) * HID + j] = f2b(fmaxf(acc[ss], 0.f));
}

// ---- layer-2 mean aggregation: 1 wave/node, 4 edges in flight, dual acc sets ----
__global__ __launch_bounds__(256) void k_agg(const u16* __restrict__ h1b, const int* __restrict__ rowp,
                                             const int* __restrict__ deg, const int* __restrict__ csrc,
                                             u16* __restrict__ mean1b) {
    int tid = threadIdx.x;
    int node = blockIdx.x * 4 + (tid >> 6);
    int lane = tid & 63;
    int half = lane >> 5, l32 = lane & 31;
    int st = rowp[node], dg = deg[node];
    int end = st + dg;
    float accA[8] = {}, accB[8] = {};
    int e = st + half;
    for (; e + 2 < end; e += 4) {
        int nb1 = csrc[e];
        int nb2 = csrc[e + 2];
        uint4 v1 = *(const uint4*)(h1b + (size_t)nb1 * HID + l32 * 8);
        uint4 v2 = *(const uint4*)(h1b + (size_t)nb2 * HID + l32 * 8);
        accA[0] += __uint_as_float(v1.x << 16);
        accA[1] += __uint_as_float(v1.x & 0xFFFF0000u);
        accA[2] += __uint_as_float(v1.y << 16);
        accA[3] += __uint_as_float(v1.y & 0xFFFF0000u);
        accA[4] += __uint_as_float(v1.z << 16);
        accA[5] += __uint_as_float(v1.z & 0xFFFF0000u);
        accA[6] += __uint_as_float(v1.w << 16);
        accA[7] += __uint_as_float(v1.w & 0xFFFF0000u);
        accB[0] += __uint_as_float(v2.x << 16);
        accB[1] += __uint_as_float(v2.x & 0xFFFF0000u);
        accB[2] += __uint_as_float(v2.y << 16);
        accB[3] += __uint_as_float(v2.y & 0xFFFF0000u);
        accB[4] += __uint_as_float(v2.z << 16);
        accB[5] += __uint_as_float(v2.z & 0xFFFF0000u);
        accB[6] += __uint_as_float(v2.w << 16);
        accB[7] += __uint_as_float(v2.w & 0xFFFF0000u);
    }
    if (e < end) {
        int nb = csrc[e];
        uint4 v = *(const uint4*)(h1b + (size_t)nb * HID + l32 * 8);
        accA[0] += __uint_as_float(v.x << 16);
        accA[1] += __uint_as_float(v.x & 0xFFFF0000u);
        accA[2] += __uint_as_float(v.y << 16);
        accA[3] += __uint_as_float(v.y & 0xFFFF0000u);
        accA[4] += __uint_as_float(v.z << 16);
        accA[5] += __uint_as_float(v.z & 0xFFFF0000u);
        accA[6] += __uint_as_float(v.w << 16);
        accA[7] += __uint_as_float(v.w & 0xFFFF0000u);
    }
    float acc[8];
#pragma unroll
    for (int j = 0; j < 8; j++) acc[j] = accA[j] + accB[j];
#pragma unroll
    for (int j = 0; j < 8; j++) acc[j] += __shfl_down(acc[j], 32);
    if (lane < 32) {
        float inv = 1.f / (float)max(dg, 1);
        uint4 o;
        o.x = (u32)f2b(acc[0] * inv) | ((u32)f2b(acc[1] * inv) << 16);
        o.y = (u32)f2b(acc[2] * inv) | ((u32)f2b(acc[3] * inv) << 16);
        o.z = (u32)f2b(acc[4] * inv) | ((u32)f2b(acc[5] * inv) << 16);
        o.w = (u32)f2b(acc[6] * inv) | ((u32)f2b(acc[7] * inv) << 16);
        *(uint4*)(mean1b + (size_t)node * HID + l32 * 8) = o;
    }
}

// ---- layer 2: bf16 MFMA GEMM + fused relu + Wout-dot + pool atomic ----
__global__ __launch_bounds__(256, 2) void k_layer2(const u16* __restrict__ mean1b, const u16* __restrict__ h1b,
                                                   const u16* __restrict__ wcat, const float* __restrict__ b2,
                                                   const int* __restrict__ batch, const float* __restrict__ Wout,
                                                   float* __restrict__ outsum) {
    __shared__ u16 As[128][40];
    __shared__ u16 Bs[256][40];
    int tid = threadIdx.x;
    int wave = tid >> 6, lane = tid & 63;
    int quad = lane >> 4, m16 = lane & 15;
    int bm = blockIdx.x;
    f32x4 acc[2][16] = {};
    for (int kt = 0; kt < 16; kt++) {
        const u16* Asrc = (kt < 8) ? mean1b : h1b;
        int kk = (kt & 7) * 32;
        __syncthreads();
#pragma unroll
        for (int i = 0; i < 2; i++) {
            int c = tid + 256 * i;
            int r = c >> 2, kc = c & 3;
            int grow = bm * 128 + r;
            uint4 v = make_uint4(0, 0, 0, 0);
            if (grow < N_N) v = *(const uint4*)(Asrc + (size_t)grow * HID + kk + kc * 8);
            *(uint4*)&As[r][kc * 8] = v;
        }
#pragma unroll
        for (int i = 0; i < 4; i++) {
            int c = tid + 256 * i;
            int n = c >> 2, kc = c & 3;
            uint4 v = *(const uint4*)(wcat + (size_t)n * 512 + kt * 32 + kc * 8);
            *(uint4*)&Bs[n][kc * 8] = v;
        }
        __syncthreads();
        bf16x8 afrag[2];
#pragma unroll
        for (int t = 0; t < 2; t++)
            afrag[t] = *(const bf16x8*)&As[wave * 32 + t * 16 + m16][quad * 8];
#pragma unroll
        for (int u = 0; u < 16; u++) {
            bf16x8 bfrag = *(const bf16x8*)&Bs[u * 16 + m16][quad * 8];
            acc[0][u] = __builtin_amdgcn_mfma_f32_16x16x32_bf16(afrag[0], bfrag, acc[0][u], 0, 0, 0);
            acc[1][u] = __builtin_amdgcn_mfma_f32_16x16x32_bf16(afrag[1], bfrag, acc[1][u], 0, 0, 0);
        }
    }
    float wo[16], bb[16];
#pragma unroll
    for (int u = 0; u < 16; u++) { int col = u * 16 + m16; wo[u] = Wout[col]; bb[u] = b2[col]; }
#pragma unroll
    for (int t = 0; t < 2; t++) {
#pragma unroll
        for (int i = 0; i < 4; i++) {
            float p = 0.f;
#pragma unroll
            for (int u = 0; u < 16; u++)
                p = fmaf(fmaxf(acc[t][u][i] + bb[u], 0.f), wo[u], p);
#pragma unroll
            for (int off = 8; off > 0; off >>= 1) p += __shfl_down(p, off, 16);
            int row = bm * 128 + wave * 32 + t * 16 + quad * 4 + i;
            if (m16 == 0 && row < N_N) atomicAdd(&outsum[batch[row]], p);
        }
    }
}

// ---- output head ----
__global__ __launch_bounds__(256) void k_out(const float* __restrict__ outsum, const float* __restrict__ gcnt,
                                             const float* __restrict__ bout, float* __restrict__ out) {
    int g = blockIdx.x * 256 + threadIdx.x;
    if (g < N_G) out[g] = outsum[g] / fmaxf(gcnt[g], 1.f) + bout[0];
}

extern "C" void kernel_launch(void* const* d_in, const int* in_sizes, int n_in,
                              void* d_out, int out_size, void* d_ws, size_t ws_size,
                              hipStream_t stream) {
    const float* x    = (const float*)d_in[0];
    const float* pos  = (const float*)d_in[1];
    const int*   ei   = (const int*)d_in[2];
    const int*   batch= (const int*)d_in[3];
    const float* W1l  = (const float*)d_in[4];
    const float* b1   = (const float*)d_in[5];
    const float* W1r  = (const float*)d_in[6];
    const float* W2l  = (const float*)d_in[7];
    const float* b2   = (const float*)d_in[8];
    const float* W2r  = (const float*)d_in[9];
    const float* Wout = (const float*)d_in[10];
    const float* bout = (const float*)d_in[11];
    float* out = (float*)d_out;
    float* ws  = (float*)d_ws;

    float* gcnt  = ws + OFF_GCNT;
    float* outs  = ws + OFF_OUTS;
    int*   rowp  = (int*)(ws + OFF_ROWP);
    int*   deg   = (int*)(ws + OFF_DEG);
    int*   bcnt  = (int*)(ws + OFF_BCNT);
    int*   tot   = (int*)(ws + OFF_TOT);
    int*   bbase = (int*)(ws + OFF_BBASE);
    u32*   ebuf  = (u32*)(ws + OFF_EBUF);
    int*   csrc  = (int*)(ws + OFF_CSRC);
    u16*   h1b   = (u16*)(ws + OFF_H1B);
    u16*   mean1b= (u16*)(ws + OFF_MEAN1B);
    u16*   wcat  = (u16*)(ws + OFF_WCAT);
    float* xp    = ws + OFF_XP;

    hipMemsetAsync(d_ws, 0, ZERO_BYTES, stream);
    k_bcnt  <<<NBLK, 256, 0, stream>>>(ei, bcnt);
    k_bscanA<<<NB, 512, 0, stream>>>(bcnt, tot);
    k_bscanB<<<1, 512, 0, stream>>>(tot, bbase);
    k_bfill <<<NBLK, 256, 0, stream>>>(ei, bcnt, bbase, ebuf);
    k_sort  <<<NB, 256, 0, stream>>>(ebuf, bbase, csrc, deg, rowp);
    k_pack  <<<(N_N * 16) / 256, 256, 0, stream>>>(x, pos, batch, xp, gcnt);
    k_wcat  <<<512, 256, 0, stream>>>(W2l, W2r, wcat);
    k_layer1<<<N_N / 16, 256, 0, stream>>>(xp, rowp, deg, csrc, W1l, b1, W1r, h1b);
    k_agg   <<<N_N / 4, 256, 0, stream>>>(h1b, rowp, deg, csrc, mean1b);
    k_layer2<<<(N_N + 127) / 128, 256, 0, stream>>>(mean1b, h1b, wcat, b2, batch, Wout, outs);
    k_out   <<<(N_G + 255) / 256, 256, 0, stream>>>(outs, gcnt, bout, out);
}